// Round 10
// baseline (144.277 us; speedup 1.0000x reference)
//
#include <hip/hip_runtime.h>

typedef _Float16 f16;
typedef _Float16 f16x8 __attribute__((ext_vector_type(8)));
typedef _Float16 f16x4 __attribute__((ext_vector_type(4)));
typedef _Float16 f16x2 __attribute__((ext_vector_type(2)));
typedef float f32x4 __attribute__((ext_vector_type(4)));
typedef float f32x16 __attribute__((ext_vector_type(16)));

#define MDIM 128
#define NDIM 256
#define CDIM 256
#define ROWS (MDIM*NDIM)   // 32768
#define L2E 1.4426950408889634f

__device__ inline int pk2(float a, float b) {
  union { f16x2 h; int i; } u;
  u.h[0] = (f16)a; u.h[1] = (f16)b;
  return u.i;
}

// ---------------- K0: weight prepack (LDS-transpose tiles) ----------------
// wq/wk/wv -> f16 [je][k], je=h*32+c (orig col j=(je&31)*8+(je>>5)); 1/sqrt(32)
// folded into wq. wf -> f16 [col][ke], ke row-permuted the same way.
__global__ __launch_bounds__(256) void k_prep(
    const float* __restrict__ wq, const float* __restrict__ wk,
    const float* __restrict__ wv, const float* __restrict__ wf,
    f16* __restrict__ bq, f16* __restrict__ bk, f16* __restrict__ bv,
    f16* __restrict__ bw)
{
  __shared__ f16 ld[16][264];
  int which = blockIdx.x >> 4, kb = blockIdx.x & 15;
  int t = threadIdx.x;
  int k0 = kb * 16;
  if (which < 3) {
    const float* W = which == 0 ? wq : which == 1 ? wk : wv;
    f16* dst       = which == 0 ? bq : which == 1 ? bk : bv;
    float sc = which == 0 ? 0.17677669529663689f : 1.0f;
#pragma unroll
    for (int r = 0; r < 16; ++r)
      ld[r][t] = (f16)(W[(size_t)(k0 + r) * 256 + t] * sc);
    __syncthreads();
    int j = (t & 31) * 8 + (t >> 5);
    f16x8 o;
#pragma unroll
    for (int i = 0; i < 8; ++i) o[i] = ld[i][j];
    *(f16x8*)(dst + (size_t)t * 256 + k0) = o;
#pragma unroll
    for (int i = 0; i < 8; ++i) o[i] = ld[8 + i][j];
    *(f16x8*)(dst + (size_t)t * 256 + k0 + 8) = o;
  } else {
#pragma unroll
    for (int r = 0; r < 16; ++r) {
      int ke = k0 + r;
      int jr = (ke & 31) * 8 + (ke >> 5);
      ld[r][t] = (f16)wf[(size_t)jr * 256 + t];
    }
    __syncthreads();
    f16x8 o;
#pragma unroll
    for (int i = 0; i < 8; ++i) o[i] = ld[i][t];
    *(f16x8*)(bw + (size_t)t * 256 + k0) = o;
#pragma unroll
    for (int i = 0; i < 8; ++i) o[i] = ld[8 + i][t];
    *(f16x8*)(bw + (size_t)t * 256 + k0 + 8) = o;
  }
}

// ---------------- K1: fused LayerNorm + QKV GEMM (r5 known-good) ----------
__global__ __launch_bounds__(256) void k_lnqkv(const float* __restrict__ x,
    const float* __restrict__ g, const float* __restrict__ bb,
    const f16* __restrict__ bq, const f16* __restrict__ bk, const f16* __restrict__ bv,
    f16* __restrict__ qo, f16* __restrict__ ko, f16* __restrict__ vT)
{
  __shared__ f16 As[64][264];
  __shared__ f16 Bs[64][264];
  __shared__ f16 vtmp[64][72];
  int bm = blockIdx.x;
  int t = threadIdx.x, lane = t & 63, w = t >> 6;
  int wr = w >> 1, wc = w & 1;
  int l15 = lane & 15, l4 = lane >> 4;
  int pr = t >> 2, pc = (t & 3) * 8;
  f16x8 pf[8];
#pragma unroll
  for (int p = 0; p < 8; ++p)
    pf[p] = *(const f16x8*)(bq + (size_t)pr * 256 + pc + p * 32);
  const float4 gv  = *(const float4*)(g + lane * 4);
  const float4 bv4 = *(const float4*)(bb + lane * 4);
#pragma unroll 4
  for (int rr = 0; rr < 16; ++rr) {
    int r = w * 16 + rr;
    const float4 xv = *(const float4*)(x + (size_t)(bm * 64 + r) * 256 + lane * 4);
    float s  = xv.x + xv.y + xv.z + xv.w;
    float s2 = xv.x*xv.x + xv.y*xv.y + xv.z*xv.z + xv.w*xv.w;
#pragma unroll
    for (int mm = 1; mm < 64; mm <<= 1) {
      s  += __shfl_xor(s,  mm, 64);
      s2 += __shfl_xor(s2, mm, 64);
    }
    float mu  = s * (1.0f / 256.0f);
    float var = s2 * (1.0f / 256.0f) - mu * mu;
    float rs  = rsqrtf(var + 1e-5f);
    f16x4 ov;
    ov[0] = (f16)((xv.x - mu) * rs * gv.x + bv4.x);
    ov[1] = (f16)((xv.y - mu) * rs * gv.y + bv4.y);
    ov[2] = (f16)((xv.z - mu) * rs * gv.z + bv4.z);
    ov[3] = (f16)((xv.w - mu) * rs * gv.w + bv4.w);
    *(f16x4*)&As[r][lane * 4] = ov;
  }
  for (int ct = 0; ct < 12; ++ct) {
    int je0 = (ct & 3) * 64;
#pragma unroll
    for (int p = 0; p < 8; ++p)
      *(f16x8*)&Bs[pr][pc + p * 32] = pf[p];
    __syncthreads();
    if (ct < 11) {
      const f16* Bn = (ct + 1) < 4 ? bq : (ct + 1) < 8 ? bk : bv;
      int je0n = ((ct + 1) & 3) * 64;
#pragma unroll
      for (int p = 0; p < 8; ++p)
        pf[p] = *(const f16x8*)(Bn + (size_t)(je0n + pr) * 256 + pc + p * 32);
    }
    f32x4 acc[2][2] = {};
#pragma unroll
    for (int kt = 0; kt < 8; ++kt) {
      f16x8 a0 = *(const f16x8*)&As[wr * 32 +      l15][kt * 32 + l4 * 8];
      f16x8 a1 = *(const f16x8*)&As[wr * 32 + 16 + l15][kt * 32 + l4 * 8];
      f16x8 b0 = *(const f16x8*)&Bs[wc * 32 +      l15][kt * 32 + l4 * 8];
      f16x8 b1 = *(const f16x8*)&Bs[wc * 32 + 16 + l15][kt * 32 + l4 * 8];
      acc[0][0] = __builtin_amdgcn_mfma_f32_16x16x32_f16(a0, b0, acc[0][0], 0, 0, 0);
      acc[0][1] = __builtin_amdgcn_mfma_f32_16x16x32_f16(a0, b1, acc[0][1], 0, 0, 0);
      acc[1][0] = __builtin_amdgcn_mfma_f32_16x16x32_f16(a1, b0, acc[1][0], 0, 0, 0);
      acc[1][1] = __builtin_amdgcn_mfma_f32_16x16x32_f16(a1, b1, acc[1][1], 0, 0, 0);
    }
    if (ct < 8) {
      f16* dst = ct < 4 ? qo : ko;
#pragma unroll
      for (int mi = 0; mi < 2; ++mi)
#pragma unroll
        for (int ni = 0; ni < 2; ++ni)
#pragma unroll
          for (int r = 0; r < 4; ++r) {
            int row = bm * 64 + wr * 32 + mi * 16 + l4 * 4 + r;
            int col = je0 + wc * 32 + ni * 16 + l15;
            dst[(size_t)row * 256 + col] = (f16)acc[mi][ni][r];
          }
    } else {
#pragma unroll
      for (int mi = 0; mi < 2; ++mi)
#pragma unroll
        for (int ni = 0; ni < 2; ++ni)
#pragma unroll
          for (int r = 0; r < 4; ++r)
            vtmp[wc * 32 + ni * 16 + l15][wr * 32 + mi * 16 + l4 * 4 + r] = (f16)acc[mi][ni][r];
      __syncthreads();
      int ch = t >> 2, np = (t & 3) * 16;
      size_t gdst = ((size_t)(bm >> 2) * 256 + je0 + ch) * 256 + (bm & 3) * 64 + np;
      *(f16x8*)(vT + gdst)     = *(const f16x8*)&vtmp[ch][np];
      *(f16x8*)(vT + gdst + 8) = *(const f16x8*)&vtmp[ch][np + 8];
    }
    __syncthreads();
  }
}

// ---------------- K2: fused attention + output projection ----------------
// Block = (m, q-quarter): 512 blocks x 128 thr (2 waves x 32 queries).
// Loop heads: stage K_h/V_h^T in LDS; swapped-QK softmax (verified machinery);
// PV computed as O^T = mfma(V, P^T) -> lane=query (rescale/normalize are
// lane-local); repack O^T (cvt_pk+shfl) into out-proj A-frags; accumulate
// outacc[32q x 256col] f32 in regs across heads; bw B-frags direct from L2.
__global__ __launch_bounds__(128) void k_attnout(const f16* __restrict__ q,
    const f16* __restrict__ k, const f16* __restrict__ vT,
    const f16* __restrict__ bw, const float* __restrict__ bias,
    float* __restrict__ out)
{
  __shared__ f16 ksh[256][40];
  __shared__ f16 vt[32][264];
  int bx = blockIdx.x;
  int m = bx >> 2, qq = bx & 3;
  int t = threadIdx.x, lane = t & 63, w = t >> 6;   // w in 0..1
  int i32 = lane & 31, hi = lane >> 5;
  size_t rowbase = (size_t)m * 256;
  int qi0 = qq * 64 + w * 32;
  f32x16 oa[8] = {};                                 // out acc: [colfrag]
  for (int h = 0; h < 8; ++h) {
    __syncthreads();                                 // prior reads done
    // stage K_h [256 x 32]
#pragma unroll
    for (int p = 0; p < 8; ++p) {
      int n = p * 32 + (t >> 2);
      int c0 = (t & 3) * 8;
      *(f16x8*)&ksh[n][c0] = *(const f16x8*)(k + (rowbase + n) * 256 + h * 32 + c0);
    }
    // stage V^T_h [32 x 256]
#pragma unroll
    for (int p = 0; p < 8; ++p) {
      int idx = p * 128 + t;
      int c = idx >> 5, nb = (idx & 31) * 8;
      *(f16x8*)&vt[c][nb] = *(const f16x8*)(vT + ((size_t)m * 256 + h * 32 + c) * 256 + nb);
    }
    __syncthreads();
    const f16* qp = q + (rowbase + qi0 + i32) * 256 + h * 32 + hi * 8;
    f16x8 qf0 = *(const f16x8*)(qp);
    f16x8 qf1 = *(const f16x8*)(qp + 16);
    f32x16 O = {};                                   // O^T: lane=q, regs=ch
    float m_run = -1e30f, l_run = 0.f;
#pragma unroll 2
    for (int kb = 0; kb < 8; ++kb) {
      f16x8 kf0 = *(const f16x8*)&ksh[kb * 32 + i32][hi * 8];
      f16x8 kf1 = *(const f16x8*)&ksh[kb * 32 + i32][16 + hi * 8];
      f32x16 s = {};
      __builtin_amdgcn_s_setprio(1);
      s = __builtin_amdgcn_mfma_f32_32x32x16_f16(kf0, qf0, s, 0, 0, 0);
      s = __builtin_amdgcn_mfma_f32_32x32x16_f16(kf1, qf1, s, 0, 0, 0);
      __builtin_amdgcn_s_setprio(0);
#pragma unroll
      for (int r = 0; r < 16; ++r) s[r] *= L2E;
      float pmax = s[0];
#pragma unroll
      for (int r = 1; r < 16; ++r) pmax = fmaxf(pmax, s[r]);
      pmax = fmaxf(pmax, __shfl_xor(pmax, 32, 64));
      if (!__all(pmax - m_run <= 8.f)) {             // defer-max
        float m_new = fmaxf(m_run, pmax);
        float f = __builtin_amdgcn_exp2f(m_run - m_new);
        l_run *= f;
#pragma unroll
        for (int r = 0; r < 16; ++r) O[r] *= f;      // lane-local (O^T!)
        m_run = m_new;
      }
      float lsum = 0.f;
#pragma unroll
      for (int r = 0; r < 16; ++r) {
        float e = __builtin_amdgcn_exp2f(s[r] - m_run);
        s[r] = e;
        lsum += e;
      }
      lsum += __shfl_xor(lsum, 32, 64);
      l_run += lsum;
      int W0[4], W1[4];
#pragma unroll
      for (int qn = 0; qn < 4; ++qn) {
        W0[qn] = pk2(s[4 * qn],     s[4 * qn + 1]);
        W1[qn] = pk2(s[4 * qn + 2], s[4 * qn + 3]);
      }
#pragma unroll
      for (int ks2 = 0; ks2 < 2; ++ks2) {
        int X0 = W0[2 * ks2], Y0 = W0[2 * ks2 + 1];
        int X1 = W1[2 * ks2], Y1 = W1[2 * ks2 + 1];
        int a0 = __shfl(X0, i32, 64),      b0 = __shfl(Y0, i32, 64);
        int a1 = __shfl(X1, i32, 64),      b1 = __shfl(Y1, i32, 64);
        int a2 = __shfl(X0, i32 + 32, 64), b2 = __shfl(Y0, i32 + 32, 64);
        int a3 = __shfl(X1, i32 + 32, 64), b3 = __shfl(Y1, i32 + 32, 64);
        union { unsigned int ww[4]; f16x8 v; } pa;
        pa.ww[0] = hi ? (unsigned)b0 : (unsigned)a0;
        pa.ww[1] = hi ? (unsigned)b1 : (unsigned)a1;
        pa.ww[2] = hi ? (unsigned)b2 : (unsigned)a2;
        pa.ww[3] = hi ? (unsigned)b3 : (unsigned)a3;
        f16x8 vb = *(const f16x8*)&vt[i32][kb * 32 + ks2 * 16 + hi * 8];
        __builtin_amdgcn_s_setprio(1);
        O = __builtin_amdgcn_mfma_f32_32x32x16_f16(vb, pa.v, O, 0, 0, 0);  // SWAPPED
        __builtin_amdgcn_s_setprio(0);
      }
    }
    // normalize (lane-local) + repack O^T -> out-proj A-frags, accumulate
    float inv = 1.f / l_run;
    int W0[4], W1[4];
#pragma unroll
    for (int qn = 0; qn < 4; ++qn) {
      W0[qn] = pk2(O[4 * qn] * inv,     O[4 * qn + 1] * inv);
      W1[qn] = pk2(O[4 * qn + 2] * inv, O[4 * qn + 3] * inv);
    }
#pragma unroll
    for (int ks2 = 0; ks2 < 2; ++ks2) {
      int X0 = W0[2 * ks2], Y0 = W0[2 * ks2 + 1];
      int X1 = W1[2 * ks2], Y1 = W1[2 * ks2 + 1];
      int a0 = __shfl(X0, i32, 64),      b0 = __shfl(Y0, i32, 64);
      int a1 = __shfl(X1, i32, 64),      b1 = __shfl(Y1, i32, 64);
      int a2 = __shfl(X0, i32 + 32, 64), b2 = __shfl(Y0, i32 + 32, 64);
      int a3 = __shfl(X1, i32 + 32, 64), b3 = __shfl(Y1, i32 + 32, 64);
      union { unsigned int ww[4]; f16x8 v; } of;
      of.ww[0] = hi ? (unsigned)b0 : (unsigned)a0;
      of.ww[1] = hi ? (unsigned)b1 : (unsigned)a1;
      of.ww[2] = hi ? (unsigned)b2 : (unsigned)a2;
      of.ww[3] = hi ? (unsigned)b3 : (unsigned)a3;
#pragma unroll
      for (int cf = 0; cf < 8; ++cf) {
        f16x8 bf = *(const f16x8*)(bw + (size_t)(cf * 32 + i32) * 256 + h * 32 + ks2 * 16 + hi * 8);
        oa[cf] = __builtin_amdgcn_mfma_f32_32x32x16_f16(of.v, bf, oa[cf], 0, 0, 0);
      }
    }
  }
  // store out + bias: C-layout lane=col (coalesced), regs=q
#pragma unroll
  for (int cf = 0; cf < 8; ++cf) {
    float bv = bias[cf * 32 + i32];
#pragma unroll
    for (int r = 0; r < 16; ++r) {
      int qrow = (r & 3) + 8 * (r >> 2) + 4 * hi;
      out[(rowbase + (size_t)(qi0 + qrow)) * 256 + cf * 32 + i32] = oa[cf][r] + bv;
    }
  }
}

extern "C" void kernel_launch(void* const* d_in, const int* in_sizes, int n_in,
                              void* d_out, int out_size, void* d_ws, size_t ws_size,
                              hipStream_t stream)
{
  const float* x  = (const float*)d_in[0];
  const float* g  = (const float*)d_in[1];
  const float* b  = (const float*)d_in[2];
  const float* wq = (const float*)d_in[3];
  const float* wk = (const float*)d_in[4];
  const float* wv = (const float*)d_in[5];
  const float* wf = (const float*)d_in[6];
  const float* bf = (const float*)d_in[7];
  float* out = (float*)d_out;

  char* ws = (char*)d_ws;
  f16* qh  = (f16*)(ws + (size_t)16 * 1024 * 1024);
  f16* kh  = (f16*)(ws + (size_t)32 * 1024 * 1024);
  f16* vTh = (f16*)(ws + (size_t)48 * 1024 * 1024);      // [m][ch][n]
  char* wbase = ws + (size_t)64 * 1024 * 1024;
  f16* bq = (f16*)(wbase);
  f16* bk = (f16*)(wbase + 128 * 1024);
  f16* bv = (f16*)(wbase + 256 * 1024);
  f16* bw = (f16*)(wbase + 384 * 1024);

  k_prep   <<<64,   256, 0, stream>>>(wq, wk, wv, wf, bq, bk, bv, bw);
  k_lnqkv  <<<512,  256, 0, stream>>>(x, g, b, bq, bk, bv, qh, kh, vTh);
  k_attnout<<<512,  128, 0, stream>>>(qh, kh, vTh, bw, bf, out);
}

// Round 11
// 97.856 us; speedup vs baseline: 1.4744x; 1.4744x over previous
//
#include <hip/hip_runtime.h>

typedef _Float16 f16;
typedef _Float16 f16x8 __attribute__((ext_vector_type(8)));
typedef _Float16 f16x4 __attribute__((ext_vector_type(4)));
typedef _Float16 f16x2 __attribute__((ext_vector_type(2)));
typedef float f32x4 __attribute__((ext_vector_type(4)));
typedef float f32x16 __attribute__((ext_vector_type(16)));

#define MDIM 128
#define NDIM 256
#define CDIM 256
#define ROWS (MDIM*NDIM)   // 32768
#define L2E 1.4426950408889634f

__device__ inline int pk2(float a, float b) {
  union { f16x2 h; int i; } u;
  u.h[0] = (f16)a; u.h[1] = (f16)b;
  return u.i;
}

// ---------------- K0: weight prepack (r9 64-block version) ----------------
__global__ __launch_bounds__(256) void k_prep(
    const float* __restrict__ wq, const float* __restrict__ wk,
    const float* __restrict__ wv, const float* __restrict__ wf,
    f16* __restrict__ bq, f16* __restrict__ bk, f16* __restrict__ bv,
    f16* __restrict__ bw)
{
  __shared__ f16 ld[16][264];
  int which = blockIdx.x >> 4, kb = blockIdx.x & 15;
  int t = threadIdx.x;
  int k0 = kb * 16;
  if (which < 3) {
    const float* W = which == 0 ? wq : which == 1 ? wk : wv;
    f16* dst       = which == 0 ? bq : which == 1 ? bk : bv;
    float sc = which == 0 ? 0.17677669529663689f : 1.0f;
#pragma unroll
    for (int r = 0; r < 16; ++r)
      ld[r][t] = (f16)(W[(size_t)(k0 + r) * 256 + t] * sc);
    __syncthreads();
    int j = (t & 31) * 8 + (t >> 5);
    f16x8 o;
#pragma unroll
    for (int i = 0; i < 8; ++i) o[i] = ld[i][j];
    *(f16x8*)(dst + (size_t)t * 256 + k0) = o;
#pragma unroll
    for (int i = 0; i < 8; ++i) o[i] = ld[8 + i][j];
    *(f16x8*)(dst + (size_t)t * 256 + k0 + 8) = o;
  } else {
#pragma unroll
    for (int r = 0; r < 16; ++r) {
      int ke = k0 + r;
      int jr = (ke & 31) * 8 + (ke >> 5);
      ld[r][t] = (f16)wf[(size_t)jr * 256 + t];
    }
    __syncthreads();
    f16x8 o;
#pragma unroll
    for (int i = 0; i < 8; ++i) o[i] = ld[i][t];
    *(f16x8*)(bw + (size_t)t * 256 + k0) = o;
#pragma unroll
    for (int i = 0; i < 8; ++i) o[i] = ld[8 + i][t];
    *(f16x8*)(bw + (size_t)t * 256 + k0 + 8) = o;
  }
}

// ---------------- K1: LayerNorm -> fp16 (wave per row) ----------------
__global__ __launch_bounds__(256) void k_ln(const float* __restrict__ x,
                                            const float* __restrict__ g,
                                            const float* __restrict__ b,
                                            f16* __restrict__ y)
{
  int row  = blockIdx.x * 4 + (threadIdx.x >> 6);
  int lane = threadIdx.x & 63;
  const float4 xv = *(const float4*)(x + (size_t)row * CDIM + lane * 4);
  float s  = xv.x + xv.y + xv.z + xv.w;
  float s2 = xv.x*xv.x + xv.y*xv.y + xv.z*xv.z + xv.w*xv.w;
#pragma unroll
  for (int m = 1; m < 64; m <<= 1) {
    s  += __shfl_xor(s,  m, 64);
    s2 += __shfl_xor(s2, m, 64);
  }
  float mu  = s * (1.0f / CDIM);
  float var = s2 * (1.0f / CDIM) - mu * mu;
  float rs  = rsqrtf(var + 1e-5f);
  const float4 gv = *(const float4*)(g + lane * 4);
  const float4 bv = *(const float4*)(b + lane * 4);
  f16x4 o;
  o[0] = (f16)((xv.x - mu) * rs * gv.x + bv.x);
  o[1] = (f16)((xv.y - mu) * rs * gv.y + bv.y);
  o[2] = (f16)((xv.z - mu) * rs * gv.z + bv.z);
  o[3] = (f16)((xv.w - mu) * rs * gv.w + bv.w);
  *(f16x4*)(y + (size_t)row * CDIM + lane * 4) = o;
}

// ---------------- K2: QKV GEMM — 128-col B-panel resident, 0-barrier loop --
// grid (mp=128, nc=6), 256 thr / 4 waves. Stage B panel [128 cols][256 K]
// once (66 KB LDS, ONE barrier), then stream 4 x 64-row tiles: per wave
// 16 rows x 128 cols = 64 MFMAs per tile, A-frags direct from L3-resident xh
// (full-line loads), stores row-major. No syncs in the loop. nc: 0-1 q,
// 2-3 k, 4-5 v (v row-major now — attn transposes during staging).
__global__ __launch_bounds__(256) void k_qkv(const f16* __restrict__ xh,
    const f16* __restrict__ bq, const f16* __restrict__ bk, const f16* __restrict__ bv,
    f16* __restrict__ qo, f16* __restrict__ ko, f16* __restrict__ vo)
{
  __shared__ f16 Bs[128][264];
  int mp = blockIdx.x;               // 256-row super-tile
  int nc = blockIdx.y;               // 0..5
  int sec = nc >> 1;
  int c0  = (nc & 1) * 128;          // col offset within the 256-col matrix
  const f16* B = sec == 0 ? bq : sec == 1 ? bk : bv;
  f16* dst     = sec == 0 ? qo : sec == 1 ? ko : vo;
  int t = threadIdx.x, lane = t & 63, w = t >> 6;
  int l15 = lane & 15, l4 = lane >> 4;
  // stage the B panel: 128 rows x 512B = 4096 16B-chunks over 256 threads
#pragma unroll
  for (int it = 0; it < 16; ++it) {
    int id = it * 256 + t;
    int br = id >> 5, bc = (id & 31) * 8;
    *(f16x8*)&Bs[br][bc] = *(const f16x8*)(B + (size_t)(c0 + br) * 256 + bc);
  }
  __syncthreads();   // the only barrier
  for (int it = 0; it < 4; ++it) {
    int r0 = mp * 256 + it * 64 + w * 16;
    f16x8 af[8];
#pragma unroll
    for (int kt = 0; kt < 8; ++kt)
      af[kt] = *(const f16x8*)(xh + (size_t)(r0 + l15) * 256 + kt * 32 + l4 * 8);
    f32x4 acc[8] = {};
#pragma unroll
    for (int kt = 0; kt < 8; ++kt) {
#pragma unroll
      for (int cf = 0; cf < 8; ++cf) {
        f16x8 bf = *(const f16x8*)&Bs[cf * 16 + l15][kt * 32 + l4 * 8];
        acc[cf] = __builtin_amdgcn_mfma_f32_16x16x32_f16(af[kt], bf, acc[cf], 0, 0, 0);
      }
    }
#pragma unroll
    for (int cf = 0; cf < 8; ++cf)
#pragma unroll
      for (int r = 0; r < 4; ++r)
        dst[(size_t)(r0 + l4 * 4 + r) * 256 + c0 + cf * 16 + l15] = (f16)acc[cf][r];
  }
}

// ---------------- K3: attention (block = (m,h), 8 waves x 32 queries) ------
// v is row-major now; transpose into vt during staging (one-time scatter).
__global__ __launch_bounds__(512, 4) void k_attn(const f16* __restrict__ q,
    const f16* __restrict__ k, const f16* __restrict__ v, f16* __restrict__ o)
{
  __shared__ f16 ks[256][40];
  __shared__ f16 vt[32][264];
  int bx = blockIdx.x;
  int m = bx >> 3, h = bx & 7;
  int t = threadIdx.x, lane = t & 63, w = t >> 6;
  int i32 = lane & 31, hi = lane >> 5;
  size_t rowbase = (size_t)m * 256;
#pragma unroll
  for (int p = 0; p < 2; ++p) {
    int n = p * 128 + (t >> 2);
    int c0 = (t & 3) * 8;
    *(f16x8*)&ks[n][c0] = *(const f16x8*)(k + (rowbase + n) * 256 + h * 32 + c0);
    f16x8 vv = *(const f16x8*)(v + (rowbase + n) * 256 + h * 32 + c0);
#pragma unroll
    for (int i = 0; i < 8; ++i) vt[c0 + i][n] = vv[i];
  }
  __syncthreads();
  int qi0 = w * 32;
  const f16* qp = q + (rowbase + qi0 + i32) * 256 + h * 32 + hi * 8;
  f16x8 qf0 = *(const f16x8*)(qp);
  f16x8 qf1 = *(const f16x8*)(qp + 16);
  f32x16 O = {};
  float m_run = -1e30f, l_run = 0.f, mL = -1e30f;
  const float RTHR = 5.545177444479562f;    // 8 / log2(e), raw domain
#pragma unroll 2
  for (int kb = 0; kb < 8; ++kb) {
    f16x8 kf0 = *(const f16x8*)&ks[kb * 32 + i32][hi * 8];
    f16x8 kf1 = *(const f16x8*)&ks[kb * 32 + i32][16 + hi * 8];
    f32x16 s = {};
    __builtin_amdgcn_s_setprio(1);
    s = __builtin_amdgcn_mfma_f32_32x32x16_f16(kf0, qf0, s, 0, 0, 0);
    s = __builtin_amdgcn_mfma_f32_32x32x16_f16(kf1, qf1, s, 0, 0, 0);
    __builtin_amdgcn_s_setprio(0);
    // tree max (raw domain)
    float m0 = fmaxf(fmaxf(s[0], s[1]),  fmaxf(s[2], s[3]));
    float m1 = fmaxf(fmaxf(s[4], s[5]),  fmaxf(s[6], s[7]));
    float m2 = fmaxf(fmaxf(s[8], s[9]),  fmaxf(s[10], s[11]));
    float m3 = fmaxf(fmaxf(s[12], s[13]), fmaxf(s[14], s[15]));
    float pmax = fmaxf(fmaxf(m0, m1), fmaxf(m2, m3));
    pmax = fmaxf(pmax, __shfl_xor(pmax, 32, 64));
    if (!__all(pmax - m_run <= RTHR)) {      // defer-max
      float m_new = fmaxf(m_run, pmax);
      float f = __builtin_amdgcn_exp2f((m_run - m_new) * L2E);
      l_run *= f;
#pragma unroll
      for (int r = 0; r < 16; ++r)
        O[r] *= __shfl(f, (r & 3) + 8 * (r >> 2) + 4 * hi, 64);
      m_run = m_new;
      mL = m_run * L2E;
    }
    float lsum = 0.f;
#pragma unroll
    for (int r = 0; r < 16; ++r) {
      float e = __builtin_amdgcn_exp2f(__builtin_fmaf(s[r], L2E, -mL));
      s[r] = e;
      lsum += e;
    }
    lsum += __shfl_xor(lsum, 32, 64);
    l_run += lsum;
    int W0[4], W1[4];
#pragma unroll
    for (int qq = 0; qq < 4; ++qq) {
      W0[qq] = pk2(s[4 * qq],     s[4 * qq + 1]);
      W1[qq] = pk2(s[4 * qq + 2], s[4 * qq + 3]);
    }
#pragma unroll
    for (int ks2 = 0; ks2 < 2; ++ks2) {
      int X0 = W0[2 * ks2], Y0 = W0[2 * ks2 + 1];
      int X1 = W1[2 * ks2], Y1 = W1[2 * ks2 + 1];
      int a0 = __shfl(X0, i32, 64),      b0 = __shfl(Y0, i32, 64);
      int a1 = __shfl(X1, i32, 64),      b1 = __shfl(Y1, i32, 64);
      int a2 = __shfl(X0, i32 + 32, 64), b2 = __shfl(Y0, i32 + 32, 64);
      int a3 = __shfl(X1, i32 + 32, 64), b3 = __shfl(Y1, i32 + 32, 64);
      union { unsigned int ww[4]; f16x8 v; } pa;
      pa.ww[0] = hi ? (unsigned)b0 : (unsigned)a0;
      pa.ww[1] = hi ? (unsigned)b1 : (unsigned)a1;
      pa.ww[2] = hi ? (unsigned)b2 : (unsigned)a2;
      pa.ww[3] = hi ? (unsigned)b3 : (unsigned)a3;
      f16x8 vb = *(const f16x8*)&vt[i32][kb * 32 + ks2 * 16 + hi * 8];
      __builtin_amdgcn_s_setprio(1);
      O = __builtin_amdgcn_mfma_f32_32x32x16_f16(pa.v, vb, O, 0, 0, 0);
      __builtin_amdgcn_s_setprio(0);
    }
  }
  float inv = 1.f / l_run;
#pragma unroll
  for (int r = 0; r < 16; ++r) {
    int i = (r & 3) + 8 * (r >> 2) + 4 * hi;
    float fr = __shfl(inv, i, 64);
    o[(rowbase + (size_t)(qi0 + i)) * 256 + h * 32 + i32] = (f16)(O[r] * fr);
  }
}

// ---------------- K4: output projection (r5 known-good) ----------------
__global__ __launch_bounds__(256) void k_out(const f16* __restrict__ a,
    const f16* __restrict__ bw, const float* __restrict__ bias,
    float* __restrict__ out)
{
  __shared__ f16 As[64][264];
  __shared__ f16 Bs[64][264];
  int bm = blockIdx.x;
  int t = threadIdx.x, lane = t & 63, w = t >> 6;
  int wr = w >> 1, wc = w & 1;
  int l15 = lane & 15, l4 = lane >> 4;
  int pr = t >> 2, pc = (t & 3) * 8;
  f16x8 pf[8];
#pragma unroll
  for (int p = 0; p < 8; ++p)
    pf[p] = *(const f16x8*)(bw + (size_t)pr * 256 + pc + p * 32);
#pragma unroll
  for (int p = 0; p < 8; ++p)
    *(f16x8*)&As[pr][pc + p * 32] = *(const f16x8*)(a + (size_t)(bm * 64 + pr) * 256 + pc + p * 32);
  for (int ct = 0; ct < 4; ++ct) {
    int col0 = ct * 64;
#pragma unroll
    for (int p = 0; p < 8; ++p)
      *(f16x8*)&Bs[pr][pc + p * 32] = pf[p];
    __syncthreads();
    if (ct < 3) {
#pragma unroll
      for (int p = 0; p < 8; ++p)
        pf[p] = *(const f16x8*)(bw + (size_t)((ct + 1) * 64 + pr) * 256 + pc + p * 32);
    }
    f32x4 acc[2][2] = {};
#pragma unroll
    for (int kt = 0; kt < 8; ++kt) {
      f16x8 a0 = *(const f16x8*)&As[wr * 32 +      l15][kt * 32 + l4 * 8];
      f16x8 a1 = *(const f16x8*)&As[wr * 32 + 16 + l15][kt * 32 + l4 * 8];
      f16x8 b0 = *(const f16x8*)&Bs[wc * 32 +      l15][kt * 32 + l4 * 8];
      f16x8 b1 = *(const f16x8*)&Bs[wc * 32 + 16 + l15][kt * 32 + l4 * 8];
      acc[0][0] = __builtin_amdgcn_mfma_f32_16x16x32_f16(a0, b0, acc[0][0], 0, 0, 0);
      acc[0][1] = __builtin_amdgcn_mfma_f32_16x16x32_f16(a0, b1, acc[0][1], 0, 0, 0);
      acc[1][0] = __builtin_amdgcn_mfma_f32_16x16x32_f16(a1, b0, acc[1][0], 0, 0, 0);
      acc[1][1] = __builtin_amdgcn_mfma_f32_16x16x32_f16(a1, b1, acc[1][1], 0, 0, 0);
    }
#pragma unroll
    for (int mi = 0; mi < 2; ++mi)
#pragma unroll
      for (int ni = 0; ni < 2; ++ni)
#pragma unroll
        for (int r = 0; r < 4; ++r) {
          int row = bm * 64 + wr * 32 + mi * 16 + l4 * 4 + r;
          int col = col0 + wc * 32 + ni * 16 + l15;
          out[(size_t)row * 256 + col] = acc[mi][ni][r] + bias[col];
        }
    __syncthreads();
  }
}

extern "C" void kernel_launch(void* const* d_in, const int* in_sizes, int n_in,
                              void* d_out, int out_size, void* d_ws, size_t ws_size,
                              hipStream_t stream)
{
  const float* x  = (const float*)d_in[0];
  const float* g  = (const float*)d_in[1];
  const float* b  = (const float*)d_in[2];
  const float* wq = (const float*)d_in[3];
  const float* wk = (const float*)d_in[4];
  const float* wv = (const float*)d_in[5];
  const float* wf = (const float*)d_in[6];
  const float* bf = (const float*)d_in[7];
  float* out = (float*)d_out;

  char* ws = (char*)d_ws;
  f16* xh  = (f16*)(ws);                                 // LN output
  f16* qh  = (f16*)(ws + (size_t)16 * 1024 * 1024);
  f16* kh  = (f16*)(ws + (size_t)32 * 1024 * 1024);
  f16* vh  = (f16*)(ws + (size_t)48 * 1024 * 1024);      // row-major now
  char* wbase = ws + (size_t)64 * 1024 * 1024;
  f16* bq = (f16*)(wbase);
  f16* bk = (f16*)(wbase + 128 * 1024);
  f16* bv = (f16*)(wbase + 256 * 1024);
  f16* bw = (f16*)(wbase + 384 * 1024);
  f16* ah = (f16*)(ws + (size_t)80 * 1024 * 1024);       // attn output

  k_prep<<<64,           256, 0, stream>>>(wq, wk, wv, wf, bq, bk, bv, bw);
  k_ln  <<<ROWS / 4,     256, 0, stream>>>(x, g, b, xh);
  k_qkv <<<dim3(128, 6), 256, 0, stream>>>(xh, bq, bk, bv, qh, kh, vh);
  k_attn<<<1024,         512, 0, stream>>>(qh, kh, vh, ah);
  k_out <<<512,          256, 0, stream>>>(ah, bw, bf, out);
}

// Round 13
// 82.128 us; speedup vs baseline: 1.7567x; 1.1915x over previous
//
#include <hip/hip_runtime.h>

typedef _Float16 f16;
typedef _Float16 f16x8 __attribute__((ext_vector_type(8)));
typedef _Float16 f16x4 __attribute__((ext_vector_type(4)));
typedef _Float16 f16x2 __attribute__((ext_vector_type(2)));
typedef float f32x4 __attribute__((ext_vector_type(4)));
typedef float f32x16 __attribute__((ext_vector_type(16)));

#define MDIM 128
#define NDIM 256
#define CDIM 256
#define ROWS (MDIM*NDIM)   // 32768
#define L2E 1.4426950408889634f

__device__ inline int pk2(float a, float b) {
  union { f16x2 h; int i; } u;
  u.h[0] = (f16)a; u.h[1] = (f16)b;
  return u.i;
}

// ---------------- K0: weight prepack (r9 coalesced version) ----------------
// wq/wk/wv -> f16 [je][k], je=h*32+c (orig col j=(je&31)*8+(je>>5)); 1/sqrt(32)
// folded into wq. wf -> f16 [col][ke], ke row-permuted the same way.
__global__ __launch_bounds__(256) void k_prep(
    const float* __restrict__ wq, const float* __restrict__ wk,
    const float* __restrict__ wv, const float* __restrict__ wf,
    f16* __restrict__ bq, f16* __restrict__ bk, f16* __restrict__ bv,
    f16* __restrict__ bw)
{
  __shared__ f16 ld[16][264];
  int which = blockIdx.x >> 4, kb = blockIdx.x & 15;
  int t = threadIdx.x;
  int k0 = kb * 16;
  if (which < 3) {
    const float* W = which == 0 ? wq : which == 1 ? wk : wv;
    f16* dst       = which == 0 ? bq : which == 1 ? bk : bv;
    float sc = which == 0 ? 0.17677669529663689f : 1.0f;
#pragma unroll
    for (int r = 0; r < 16; ++r)
      ld[r][t] = (f16)(W[(size_t)(k0 + r) * 256 + t] * sc);
    __syncthreads();
    int j = (t & 31) * 8 + (t >> 5);
    f16x8 o;
#pragma unroll
    for (int i = 0; i < 8; ++i) o[i] = ld[i][j];
    *(f16x8*)(dst + (size_t)t * 256 + k0) = o;
#pragma unroll
    for (int i = 0; i < 8; ++i) o[i] = ld[8 + i][j];
    *(f16x8*)(dst + (size_t)t * 256 + k0 + 8) = o;
  } else {
#pragma unroll
    for (int r = 0; r < 16; ++r) {
      int ke = k0 + r;
      int jr = (ke & 31) * 8 + (ke >> 5);
      ld[r][t] = (f16)wf[(size_t)jr * 256 + t];
    }
    __syncthreads();
    f16x8 o;
#pragma unroll
    for (int i = 0; i < 8; ++i) o[i] = ld[i][t];
    *(f16x8*)(bw + (size_t)t * 256 + k0) = o;
#pragma unroll
    for (int i = 0; i < 8; ++i) o[i] = ld[8 + i][t];
    *(f16x8*)(bw + (size_t)t * 256 + k0 + 8) = o;
  }
}

// ---------------- K1: fused LayerNorm + QKV GEMM (r5 exact) ----------------
__global__ __launch_bounds__(256) void k_lnqkv(const float* __restrict__ x,
    const float* __restrict__ g, const float* __restrict__ bb,
    const f16* __restrict__ bq, const f16* __restrict__ bk, const f16* __restrict__ bv,
    f16* __restrict__ qo, f16* __restrict__ ko, f16* __restrict__ vT)
{
  __shared__ f16 As[64][264];
  __shared__ f16 Bs[64][264];
  __shared__ f16 vtmp[64][72];
  int bm = blockIdx.x;
  int t = threadIdx.x, lane = t & 63, w = t >> 6;
  int wr = w >> 1, wc = w & 1;
  int l15 = lane & 15, l4 = lane >> 4;
  int pr = t >> 2, pc = (t & 3) * 8;
  f16x8 pf[8];
#pragma unroll
  for (int p = 0; p < 8; ++p)
    pf[p] = *(const f16x8*)(bq + (size_t)pr * 256 + pc + p * 32);
  const float4 gv  = *(const float4*)(g + lane * 4);
  const float4 bv4 = *(const float4*)(bb + lane * 4);
#pragma unroll 4
  for (int rr = 0; rr < 16; ++rr) {
    int r = w * 16 + rr;
    const float4 xv = *(const float4*)(x + (size_t)(bm * 64 + r) * 256 + lane * 4);
    float s  = xv.x + xv.y + xv.z + xv.w;
    float s2 = xv.x*xv.x + xv.y*xv.y + xv.z*xv.z + xv.w*xv.w;
#pragma unroll
    for (int mm = 1; mm < 64; mm <<= 1) {
      s  += __shfl_xor(s,  mm, 64);
      s2 += __shfl_xor(s2, mm, 64);
    }
    float mu  = s * (1.0f / 256.0f);
    float var = s2 * (1.0f / 256.0f) - mu * mu;
    float rs  = rsqrtf(var + 1e-5f);
    f16x4 ov;
    ov[0] = (f16)((xv.x - mu) * rs * gv.x + bv4.x);
    ov[1] = (f16)((xv.y - mu) * rs * gv.y + bv4.y);
    ov[2] = (f16)((xv.z - mu) * rs * gv.z + bv4.z);
    ov[3] = (f16)((xv.w - mu) * rs * gv.w + bv4.w);
    *(f16x4*)&As[r][lane * 4] = ov;
  }
  for (int ct = 0; ct < 12; ++ct) {
    int je0 = (ct & 3) * 64;
#pragma unroll
    for (int p = 0; p < 8; ++p)
      *(f16x8*)&Bs[pr][pc + p * 32] = pf[p];
    __syncthreads();
    if (ct < 11) {
      const f16* Bn = (ct + 1) < 4 ? bq : (ct + 1) < 8 ? bk : bv;
      int je0n = ((ct + 1) & 3) * 64;
#pragma unroll
      for (int p = 0; p < 8; ++p)
        pf[p] = *(const f16x8*)(Bn + (size_t)(je0n + pr) * 256 + pc + p * 32);
    }
    f32x4 acc[2][2] = {};
#pragma unroll
    for (int kt = 0; kt < 8; ++kt) {
      f16x8 a0 = *(const f16x8*)&As[wr * 32 +      l15][kt * 32 + l4 * 8];
      f16x8 a1 = *(const f16x8*)&As[wr * 32 + 16 + l15][kt * 32 + l4 * 8];
      f16x8 b0 = *(const f16x8*)&Bs[wc * 32 +      l15][kt * 32 + l4 * 8];
      f16x8 b1 = *(const f16x8*)&Bs[wc * 32 + 16 + l15][kt * 32 + l4 * 8];
      acc[0][0] = __builtin_amdgcn_mfma_f32_16x16x32_f16(a0, b0, acc[0][0], 0, 0, 0);
      acc[0][1] = __builtin_amdgcn_mfma_f32_16x16x32_f16(a0, b1, acc[0][1], 0, 0, 0);
      acc[1][0] = __builtin_amdgcn_mfma_f32_16x16x32_f16(a1, b0, acc[1][0], 0, 0, 0);
      acc[1][1] = __builtin_amdgcn_mfma_f32_16x16x32_f16(a1, b1, acc[1][1], 0, 0, 0);
    }
    if (ct < 8) {
      f16* dst = ct < 4 ? qo : ko;
#pragma unroll
      for (int mi = 0; mi < 2; ++mi)
#pragma unroll
        for (int ni = 0; ni < 2; ++ni)
#pragma unroll
          for (int r = 0; r < 4; ++r) {
            int row = bm * 64 + wr * 32 + mi * 16 + l4 * 4 + r;
            int col = je0 + wc * 32 + ni * 16 + l15;
            dst[(size_t)row * 256 + col] = (f16)acc[mi][ni][r];
          }
    } else {
#pragma unroll
      for (int mi = 0; mi < 2; ++mi)
#pragma unroll
        for (int ni = 0; ni < 2; ++ni)
#pragma unroll
          for (int r = 0; r < 4; ++r)
            vtmp[wc * 32 + ni * 16 + l15][wr * 32 + mi * 16 + l4 * 4 + r] = (f16)acc[mi][ni][r];
      __syncthreads();
      int ch = t >> 2, np = (t & 3) * 16;
      size_t gdst = ((size_t)(bm >> 2) * 256 + je0 + ch) * 256 + (bm & 3) * 64 + np;
      *(f16x8*)(vT + gdst)     = *(const f16x8*)&vtmp[ch][np];
      *(f16x8*)(vT + gdst + 8) = *(const f16x8*)&vtmp[ch][np + 8];
    }
    __syncthreads();
  }
}

// ---------------- K2: attention (r5 exact) ----------------
__global__ __launch_bounds__(512, 4) void k_attn(const f16* __restrict__ q,
    const f16* __restrict__ k, const f16* __restrict__ vT, f16* __restrict__ o)
{
  __shared__ f16 ks[256][40];
  __shared__ f16 vt[32][264];
  int bx = blockIdx.x;
  int m = bx >> 3, h = bx & 7;
  int t = threadIdx.x, lane = t & 63, w = t >> 6;
  int i32 = lane & 31, hi = lane >> 5;
  size_t rowbase = (size_t)m * 256;
#pragma unroll
  for (int p = 0; p < 2; ++p) {
    int n = p * 128 + (t >> 2);
    int c0 = (t & 3) * 8;
    *(f16x8*)&ks[n][c0] = *(const f16x8*)(k + (rowbase + n) * 256 + h * 32 + c0);
  }
#pragma unroll
  for (int p = 0; p < 2; ++p) {
    int idx = p * 512 + t;
    int c = idx >> 5, nb = (idx & 31) * 8;
    *(f16x8*)&vt[c][nb] = *(const f16x8*)(vT + ((size_t)m * 256 + h * 32 + c) * 256 + nb);
  }
  __syncthreads();
  int qi0 = w * 32;
  const f16* qp = q + (rowbase + qi0 + i32) * 256 + h * 32 + hi * 8;
  f16x8 qf0 = *(const f16x8*)(qp);
  f16x8 qf1 = *(const f16x8*)(qp + 16);
  f32x16 O = {};
  float m_run = -1e30f, l_run = 0.f;
#pragma unroll 2
  for (int kb = 0; kb < 8; ++kb) {
    f16x8 kf0 = *(const f16x8*)&ks[kb * 32 + i32][hi * 8];
    f16x8 kf1 = *(const f16x8*)&ks[kb * 32 + i32][16 + hi * 8];
    f32x16 s = {};
    __builtin_amdgcn_s_setprio(1);
    s = __builtin_amdgcn_mfma_f32_32x32x16_f16(kf0, qf0, s, 0, 0, 0);
    s = __builtin_amdgcn_mfma_f32_32x32x16_f16(kf1, qf1, s, 0, 0, 0);
    __builtin_amdgcn_s_setprio(0);
#pragma unroll
    for (int r = 0; r < 16; ++r) s[r] *= L2E;
    float pmax = s[0];
#pragma unroll
    for (int r = 1; r < 16; ++r) pmax = fmaxf(pmax, s[r]);
    pmax = fmaxf(pmax, __shfl_xor(pmax, 32, 64));
    if (!__all(pmax - m_run <= 8.f)) {
      float m_new = fmaxf(m_run, pmax);
      float f = __builtin_amdgcn_exp2f(m_run - m_new);
      l_run *= f;
#pragma unroll
      for (int r = 0; r < 16; ++r)
        O[r] *= __shfl(f, (r & 3) + 8 * (r >> 2) + 4 * hi, 64);
      m_run = m_new;
    }
    float lsum = 0.f;
#pragma unroll
    for (int r = 0; r < 16; ++r) {
      float e = __builtin_amdgcn_exp2f(s[r] - m_run);
      s[r] = e;
      lsum += e;
    }
    lsum += __shfl_xor(lsum, 32, 64);
    l_run += lsum;
    int W0[4], W1[4];
#pragma unroll
    for (int qq = 0; qq < 4; ++qq) {
      W0[qq] = pk2(s[4 * qq],     s[4 * qq + 1]);
      W1[qq] = pk2(s[4 * qq + 2], s[4 * qq + 3]);
    }
#pragma unroll
    for (int ks2 = 0; ks2 < 2; ++ks2) {
      int X0 = W0[2 * ks2], Y0 = W0[2 * ks2 + 1];
      int X1 = W1[2 * ks2], Y1 = W1[2 * ks2 + 1];
      int a0 = __shfl(X0, i32, 64),      b0 = __shfl(Y0, i32, 64);
      int a1 = __shfl(X1, i32, 64),      b1 = __shfl(Y1, i32, 64);
      int a2 = __shfl(X0, i32 + 32, 64), b2 = __shfl(Y0, i32 + 32, 64);
      int a3 = __shfl(X1, i32 + 32, 64), b3 = __shfl(Y1, i32 + 32, 64);
      union { unsigned int ww[4]; f16x8 v; } pa;
      pa.ww[0] = hi ? (unsigned)b0 : (unsigned)a0;
      pa.ww[1] = hi ? (unsigned)b1 : (unsigned)a1;
      pa.ww[2] = hi ? (unsigned)b2 : (unsigned)a2;
      pa.ww[3] = hi ? (unsigned)b3 : (unsigned)a3;
      f16x8 vb = *(const f16x8*)&vt[i32][kb * 32 + ks2 * 16 + hi * 8];
      __builtin_amdgcn_s_setprio(1);
      O = __builtin_amdgcn_mfma_f32_32x32x16_f16(pa.v, vb, O, 0, 0, 0);
      __builtin_amdgcn_s_setprio(0);
    }
  }
  float inv = 1.f / l_run;
#pragma unroll
  for (int r = 0; r < 16; ++r) {
    int i = (r & 3) + 8 * (r >> 2) + 4 * hi;
    float fr = __shfl(inv, i, 64);
    o[(rowbase + (size_t)(qi0 + i)) * 256 + h * 32 + i32] = (f16)(O[r] * fr);
  }
}

// ---------------- K3: output projection (r5 exact) ----------------
__global__ __launch_bounds__(256) void k_out(const f16* __restrict__ a,
    const f16* __restrict__ bw, const float* __restrict__ bias,
    float* __restrict__ out)
{
  __shared__ f16 As[64][264];
  __shared__ f16 Bs[64][264];
  int bm = blockIdx.x;
  int t = threadIdx.x, lane = t & 63, w = t >> 6;
  int wr = w >> 1, wc = w & 1;
  int l15 = lane & 15, l4 = lane >> 4;
  int pr = t >> 2, pc = (t & 3) * 8;
  f16x8 pf[8];
#pragma unroll
  for (int p = 0; p < 8; ++p)
    pf[p] = *(const f16x8*)(bw + (size_t)pr * 256 + pc + p * 32);
#pragma unroll
  for (int p = 0; p < 8; ++p)
    *(f16x8*)&As[pr][pc + p * 32] = *(const f16x8*)(a + (size_t)(bm * 64 + pr) * 256 + pc + p * 32);
  for (int ct = 0; ct < 4; ++ct) {
    int col0 = ct * 64;
#pragma unroll
    for (int p = 0; p < 8; ++p)
      *(f16x8*)&Bs[pr][pc + p * 32] = pf[p];
    __syncthreads();
    if (ct < 3) {
#pragma unroll
      for (int p = 0; p < 8; ++p)
        pf[p] = *(const f16x8*)(bw + (size_t)((ct + 1) * 64 + pr) * 256 + pc + p * 32);
    }
    f32x4 acc[2][2] = {};
#pragma unroll
    for (int kt = 0; kt < 8; ++kt) {
      f16x8 a0 = *(const f16x8*)&As[wr * 32 +      l15][kt * 32 + l4 * 8];
      f16x8 a1 = *(const f16x8*)&As[wr * 32 + 16 + l15][kt * 32 + l4 * 8];
      f16x8 b0 = *(const f16x8*)&Bs[wc * 32 +      l15][kt * 32 + l4 * 8];
      f16x8 b1 = *(const f16x8*)&Bs[wc * 32 + 16 + l15][kt * 32 + l4 * 8];
      acc[0][0] = __builtin_amdgcn_mfma_f32_16x16x32_f16(a0, b0, acc[0][0], 0, 0, 0);
      acc[0][1] = __builtin_amdgcn_mfma_f32_16x16x32_f16(a0, b1, acc[0][1], 0, 0, 0);
      acc[1][0] = __builtin_amdgcn_mfma_f32_16x16x32_f16(a1, b0, acc[1][0], 0, 0, 0);
      acc[1][1] = __builtin_amdgcn_mfma_f32_16x16x32_f16(a1, b1, acc[1][1], 0, 0, 0);
    }
#pragma unroll
    for (int mi = 0; mi < 2; ++mi)
#pragma unroll
      for (int ni = 0; ni < 2; ++ni)
#pragma unroll
        for (int r = 0; r < 4; ++r) {
          int row = bm * 64 + wr * 32 + mi * 16 + l4 * 4 + r;
          int col = col0 + wc * 32 + ni * 16 + l15;
          out[(size_t)row * 256 + col] = acc[mi][ni][r] + bias[col];
        }
    __syncthreads();
  }
}

extern "C" void kernel_launch(void* const* d_in, const int* in_sizes, int n_in,
                              void* d_out, int out_size, void* d_ws, size_t ws_size,
                              hipStream_t stream)
{
  const float* x  = (const float*)d_in[0];
  const float* g  = (const float*)d_in[1];
  const float* b  = (const float*)d_in[2];
  const float* wq = (const float*)d_in[3];
  const float* wk = (const float*)d_in[4];
  const float* wv = (const float*)d_in[5];
  const float* wf = (const float*)d_in[6];
  const float* bf = (const float*)d_in[7];
  float* out = (float*)d_out;

  char* ws = (char*)d_ws;
  f16* ah  = (f16*)(ws);                                 // attn output
  f16* qh  = (f16*)(ws + (size_t)16 * 1024 * 1024);
  f16* kh  = (f16*)(ws + (size_t)32 * 1024 * 1024);
  f16* vTh = (f16*)(ws + (size_t)48 * 1024 * 1024);      // [m][ch][n]
  char* wbase = ws + (size_t)64 * 1024 * 1024;
  f16* bq = (f16*)(wbase);
  f16* bk = (f16*)(wbase + 128 * 1024);
  f16* bv = (f16*)(wbase + 256 * 1024);
  f16* bw = (f16*)(wbase + 384 * 1024);

  k_prep <<<64,   256, 0, stream>>>(wq, wk, wv, wf, bq, bk, bv, bw);
  k_lnqkv<<<512,  256, 0, stream>>>(x, g, b, bq, bk, bv, qh, kh, vTh);
  k_attn <<<1024, 512, 0, stream>>>(qh, kh, vTh, ah);
  k_out  <<<512,  256, 0, stream>>>(ah, bw, bf, out);
}